// Round 3
// baseline (594.502 us; speedup 1.0000x reference)
//
#include <hip/hip_runtime.h>
#include <hip/hip_bf16.h>

#define N_NODES 50000
#define N_EDGES 600000
#define D_IN 256
#define D 128

#define SCAN_CHUNK 1024
#define N_CHUNKS ((N_NODES + SCAN_CHUNK - 1) / SCAN_CHUNK)  // 49

typedef unsigned short ushort_t;

__device__ __forceinline__ float bf2f(ushort_t u) {
  union { unsigned int i; float f; } v;
  v.i = ((unsigned int)u) << 16;
  return v.f;
}

// ---------------- dtype detection ----------------
// Probe each float-family input as packed bf16. fp32 data's low half-words are
// mantissa garbage (~56% sane as bf16); true bf16 data is ~100% sane.
// flags[a]=1 -> array a is bf16.
__global__ void k_detect(const void* e, const void* wn, const void* bn,
                         const void* w1, const void* b1, const void* w2,
                         const void* b2, int* flags) {
  const void* ptrs[7] = {e, wn, bn, w1, b1, w2, b2};
  const int ns[7] = {12800000, 32768, 128, 16384, 128, 16384, 128};
  __shared__ int red[256];
  int t = threadIdx.x;
  for (int a = 0; a < 7; a++) {
    int pn = ns[a] < 2048 ? ns[a] : 2048;
    const ushort_t* p = (const ushort_t*)ptrs[a];
    int cnt = 0;
    for (int i = t; i < pn; i += 256) {
      ushort_t u = p[i];
      int ex = (u >> 7) & 0xFF;
      if ((u & 0x7FFF) == 0 || (ex >= 100 && ex <= 130)) cnt++;
    }
    red[t] = cnt;
    __syncthreads();
    for (int off = 128; off > 0; off >>= 1) {
      if (t < off) red[t] += red[t + off];
      __syncthreads();
    }
    if (t == 0) flags[a] = (red[0] * 100 >= pn * 85) ? 1 : 0;
    __syncthreads();
  }
}

// Canonicalize weights/biases to fp32 in ws.
// Float offsets: Wn [0,32768) bn [32768,32896) w1 [32896,49280)
//                b1 [49280,49408) w2 [49408,65792) b2 [65792,65920)
__global__ void k_convert(const void* wn, const void* bn, const void* w1,
                          const void* b1, const void* w2, const void* b2,
                          const int* __restrict__ flags, float* __restrict__ out) {
  int i = blockIdx.x * blockDim.x + threadIdx.x;
  if (i >= 65920) return;
  const void* src; int off; int fl;
  if (i < 32768)      { src = wn; off = 0;     fl = flags[1]; }
  else if (i < 32896) { src = bn; off = 32768; fl = flags[2]; }
  else if (i < 49280) { src = w1; off = 32896; fl = flags[3]; }
  else if (i < 49408) { src = b1; off = 49280; fl = flags[4]; }
  else if (i < 65792) { src = w2; off = 49408; fl = flags[5]; }
  else                { src = b2; off = 65792; fl = flags[6]; }
  int j = i - off;
  out[i] = fl ? bf2f(((const ushort_t*)src)[j]) : ((const float*)src)[j];
}

// ---------------- CSR build ----------------

__global__ void k_deg(const int* __restrict__ dst, int* __restrict__ deg) {
  int e = blockIdx.x * blockDim.x + threadIdx.x;
  if (e < N_EDGES) atomicAdd(&deg[dst[e]], 1);
}

__global__ void k_partial(const int* __restrict__ deg, int* __restrict__ partial) {
  __shared__ int lds[256];
  int b = blockIdx.x, t = threadIdx.x;
  int base = b * SCAN_CHUNK + t * 4;
  int s = 0;
#pragma unroll
  for (int i = 0; i < 4; i++) {
    int idx = base + i;
    if (idx < N_NODES) s += deg[idx];
  }
  lds[t] = s;
  __syncthreads();
  for (int off = 128; off > 0; off >>= 1) {
    if (t < off) lds[t] += lds[t + off];
    __syncthreads();
  }
  if (t == 0) partial[b] = lds[0];
}

__global__ void k_scan_part(int* __restrict__ partial, int* __restrict__ row_start) {
  if (threadIdx.x == 0) {
    int run = 0;
    for (int i = 0; i < N_CHUNKS; i++) {
      int v = partial[i];
      partial[i] = run;
      run += v;
    }
    row_start[N_NODES] = run;  // == N_EDGES
  }
}

__global__ void k_scan_final(const int* __restrict__ deg, const int* __restrict__ partial,
                             int* __restrict__ row_start, float* __restrict__ dinv) {
  __shared__ int lds[256];
  int b = blockIdx.x, t = threadIdx.x;
  int base = b * SCAN_CHUNK + t * 4;
  int v[4];
  int s = 0;
#pragma unroll
  for (int i = 0; i < 4; i++) {
    int idx = base + i;
    v[i] = (idx < N_NODES) ? deg[idx] : 0;
    s += v[i];
  }
  lds[t] = s;
  __syncthreads();
  for (int off = 1; off < 256; off <<= 1) {
    int add = (t >= off) ? lds[t - off] : 0;
    __syncthreads();
    lds[t] += add;
    __syncthreads();
  }
  int excl = lds[t] - s + partial[b];
#pragma unroll
  for (int i = 0; i < 4; i++) {
    int idx = base + i;
    if (idx < N_NODES) {
      row_start[idx] = excl;
      dinv[idx] = rsqrtf((float)(v[i] + 1));  // +1 self-loop
      excl += v[i];
    }
  }
}

__global__ void k_fill(const int* __restrict__ src, const int* __restrict__ dst,
                       const int* __restrict__ row_start, int* __restrict__ cursor,
                       int* __restrict__ csr) {
  int e = blockIdx.x * blockDim.x + threadIdx.x;
  if (e < N_EDGES) {
    int d = dst[e];
    int pos = atomicAdd(&cursor[d], 1);
    csr[row_start[d] + pos] = src[e];
  }
}

// ---------------- embed gather + GEMM (256 -> 128) ----------------
// out[n][j] = sum_k embed[tok[n]][k] * W[j][k] + b[j]
#define EG_NPB 8
__global__ __launch_bounds__(256) void k_embed_gemm(
    const int* __restrict__ tokens, const void* __restrict__ embed_v,
    const int* __restrict__ flags, const float* __restrict__ W,
    const float* __restrict__ bias, float* __restrict__ out) {
  __shared__ float w_lds[128 * 65];      // 33,280 B; stride 65 -> 2-way banks (free)
  __shared__ float x_lds[EG_NPB][D_IN];  // 8 KB
  int tid = threadIdx.x;
  int j = tid & 127;
  int g = tid >> 7;  // 0..1, wave-uniform
  int node0 = blockIdx.x * EG_NPB;

  int fl = flags[0];  // 1 -> embed table is bf16, 0 -> fp32
  const ushort_t* eb = (const ushort_t*)embed_v;
  const float* ef = (const float*)embed_v;

  for (int idx = tid; idx < EG_NPB * D_IN; idx += 256) {
    int n = idx >> 8;
    int k = idx & 255;
    size_t o = (size_t)tokens[node0 + n] * D_IN + k;
    x_lds[n][k] = fl ? bf2f(eb[o]) : ef[o];
  }

  float acc[4] = {0.f, 0.f, 0.f, 0.f};

  for (int k0 = 0; k0 < D_IN; k0 += 64) {
    __syncthreads();
    for (int idx = tid; idx < 128 * 64; idx += 256) {
      int jj = idx >> 6;
      int kk = idx & 63;
      w_lds[jj * 65 + kk] = W[jj * D_IN + k0 + kk];
    }
    __syncthreads();
#pragma unroll 4
    for (int kk = 0; kk < 64; kk++) {
      float wv = w_lds[j * 65 + kk];
#pragma unroll
      for (int m = 0; m < 4; m++)
        acc[m] += wv * x_lds[g * 4 + m][k0 + kk];
    }
  }
  float bv = bias[j];
#pragma unroll
  for (int m = 0; m < 4; m++) {
    int node = node0 + g * 4 + m;
    out[(size_t)node * D + j] = acc[m] + bv;  // 50000 % 8 == 0
  }
}

// ---------------- GEMM 128x128: out = x @ W^T ----------------
#define G_NPB 8
__global__ __launch_bounds__(256) void k_gemm128(
    const float* __restrict__ x, const float* __restrict__ W,
    float* __restrict__ out) {
  __shared__ float w_lds[128 * 65];
  __shared__ float x_lds[G_NPB][D];
  int tid = threadIdx.x;
  int j = tid & 127;
  int g = tid >> 7;
  int node0 = blockIdx.x * G_NPB;

  for (int idx = tid; idx < G_NPB * D; idx += 256) {
    int n = idx >> 7;
    int k = idx & 127;
    x_lds[n][k] = x[(size_t)(node0 + n) * D + k];
  }
  float acc[4] = {0.f, 0.f, 0.f, 0.f};
  for (int k0 = 0; k0 < D; k0 += 64) {
    __syncthreads();
    for (int idx = tid; idx < 128 * 64; idx += 256) {
      int jj = idx >> 6;
      int kk = idx & 63;
      w_lds[jj * 65 + kk] = W[jj * D + k0 + kk];
    }
    __syncthreads();
#pragma unroll 4
    for (int kk = 0; kk < 64; kk++) {
      float wv = w_lds[j * 65 + kk];
#pragma unroll
      for (int m = 0; m < 4; m++)
        acc[m] += wv * x_lds[g * 4 + m][k0 + kk];
    }
  }
#pragma unroll
  for (int m = 0; m < 4; m++) {
    int node = node0 + g * 4 + m;
    out[(size_t)node * D + j] = acc[m];
  }
}

// ---------------- aggregation ----------------
// out[d] = sum_{s->d} dinv[s]dinv[d] t[s] + dinv[d]^2 t[d] + b  (one wave per d)
// Output is ALWAYS fp32 (reference output dtype is float32).
template <bool RELU>
__global__ __launch_bounds__(256) void k_aggregate(
    const float* __restrict__ t, const int* __restrict__ row_start,
    const int* __restrict__ csr, const float* __restrict__ dinv,
    const float* __restrict__ bias, float* __restrict__ out) {
  int wave = threadIdx.x >> 6;
  int lane = threadIdx.x & 63;
  int node = blockIdx.x * 4 + wave;
  if (node >= N_NODES) return;
  float di = dinv[node];
  const float2* t2 = (const float2*)t;
  float2 acc;
  {
    float2 v = t2[(size_t)node * 64 + lane];  // self-loop
    float w = di * di;
    acc.x = w * v.x;
    acc.y = w * v.y;
  }
  int e0 = row_start[node], e1 = row_start[node + 1];
  for (int e = e0; e < e1; e++) {
    int s = csr[e];
    float w = di * dinv[s];
    float2 v = t2[(size_t)s * 64 + lane];
    acc.x += w * v.x;
    acc.y += w * v.y;
  }
  acc.x += bias[2 * lane];
  acc.y += bias[2 * lane + 1];
  if (RELU) {
    acc.x = fmaxf(acc.x, 0.f);
    acc.y = fmaxf(acc.y, 0.f);
  }
  *(float2*)&out[(size_t)node * D + 2 * lane] = acc;
}

extern "C" void kernel_launch(void* const* d_in, const int* in_sizes, int n_in,
                              void* d_out, int out_size, void* d_ws, size_t ws_size,
                              hipStream_t stream) {
  const int* tokens = (const int*)d_in[0];
  const int* edge = (const int*)d_in[1];  // [2][E]
  const void* embed = d_in[2];
  const void* Wn = d_in[3];
  const void* bn = d_in[4];
  const void* w1 = d_in[5];
  const void* b1 = d_in[6];
  const void* w2 = d_in[7];
  const void* b2 = d_in[8];
  float* out = (float*)d_out;  // float32 output per reference dtype

  const int* src = edge;
  const int* dst = edge + N_EDGES;

  char* ws = (char*)d_ws;
  float* A = (float*)ws;                       // 25,600,000 B
  float* B = (float*)(ws + 25600000);          // 25,600,000 B
  float* dinv = (float*)(ws + 51200000);       // 200,000 B
  int* row_start = (int*)(ws + 51400064);      // 200,004 B
  int* degcur = (int*)(ws + 51600192);         // 200,000 B (deg, then cursor)
  int* csr = (int*)(ws + 51800256);            // 2,400,000 B
  int* partial = (int*)(ws + 54200320);        // 196 B
  int* flags = (int*)(ws + 54200576);          // 28 B
  float* wf = (float*)(ws + 54200640);         // 65,920 floats = 263,680 B
  const float* Wnf = wf;
  const float* bnf = wf + 32768;
  const float* w1f = wf + 32896;
  const float* b1f = wf + 49280;
  const float* w2f = wf + 49408;
  const float* b2f = wf + 65792;

  // --- dtype detect + canonicalize params to fp32 ---
  k_detect<<<1, 256, 0, stream>>>(embed, Wn, bn, w1, b1, w2, b2, flags);
  k_convert<<<(65920 + 255) / 256, 256, 0, stream>>>(Wn, bn, w1, b1, w2, b2, flags, wf);

  // --- CSR build (shared by both convs) ---
  hipMemsetAsync(degcur, 0, N_NODES * sizeof(int), stream);
  k_deg<<<(N_EDGES + 255) / 256, 256, 0, stream>>>(dst, degcur);
  k_partial<<<N_CHUNKS, 256, 0, stream>>>(degcur, partial);
  k_scan_part<<<1, 64, 0, stream>>>(partial, row_start);
  k_scan_final<<<N_CHUNKS, 256, 0, stream>>>(degcur, partial, row_start, dinv);
  hipMemsetAsync(degcur, 0, N_NODES * sizeof(int), stream);
  k_fill<<<(N_EDGES + 255) / 256, 256, 0, stream>>>(src, dst, row_start, degcur, csr);

  // --- x0 = embed[tokens] @ Wn^T + bn ---
  k_embed_gemm<<<N_NODES / EG_NPB, 256, 0, stream>>>(tokens, embed, flags, Wnf, bnf, A);

  // --- conv1: t = x0 @ w1^T ; aggregate + b1 + relu -> A ---
  k_gemm128<<<N_NODES / G_NPB, 256, 0, stream>>>(A, w1f, B);
  k_aggregate<true><<<(N_NODES + 3) / 4, 256, 0, stream>>>(
      B, row_start, csr, dinv, b1f, A);

  // --- conv2: t = x1 @ w2^T ; aggregate + b2 -> out (fp32) ---
  k_gemm128<<<N_NODES / G_NPB, 256, 0, stream>>>(A, w2f, B);
  k_aggregate<false><<<(N_NODES + 3) / 4, 256, 0, stream>>>(
      B, row_start, csr, dinv, b2f, out);
}

// Round 4
// 461.173 us; speedup vs baseline: 1.2891x; 1.2891x over previous
//
#include <hip/hip_runtime.h>
#include <hip/hip_bf16.h>

#define N_NODES 50000
#define N_EDGES 600000
#define D_IN 256
#define D 128

#define SCAN_CHUNK 1024
#define N_CHUNKS ((N_NODES + SCAN_CHUNK - 1) / SCAN_CHUNK)  // 49

typedef unsigned short ushort_t;

__device__ __forceinline__ float bf2f(ushort_t u) {
  union { unsigned int i; float f; } v;
  v.i = ((unsigned int)u) << 16;
  return v.f;
}

// ---------------- dtype detection ----------------
__global__ void k_detect(const void* e, const void* wn, const void* bn,
                         const void* w1, const void* b1, const void* w2,
                         const void* b2, int* flags) {
  const void* ptrs[7] = {e, wn, bn, w1, b1, w2, b2};
  const int ns[7] = {12800000, 32768, 128, 16384, 128, 16384, 128};
  __shared__ int red[256];
  int t = threadIdx.x;
  for (int a = 0; a < 7; a++) {
    int pn = ns[a] < 2048 ? ns[a] : 2048;
    const ushort_t* p = (const ushort_t*)ptrs[a];
    int cnt = 0;
    for (int i = t; i < pn; i += 256) {
      ushort_t u = p[i];
      int ex = (u >> 7) & 0xFF;
      if ((u & 0x7FFF) == 0 || (ex >= 100 && ex <= 130)) cnt++;
    }
    red[t] = cnt;
    __syncthreads();
    for (int off = 128; off > 0; off >>= 1) {
      if (t < off) red[t] += red[t + off];
      __syncthreads();
    }
    if (t == 0) flags[a] = (red[0] * 100 >= pn * 85) ? 1 : 0;
    __syncthreads();
  }
}

// Canonicalize weights/biases to fp32 in ws.
__global__ void k_convert(const void* wn, const void* bn, const void* w1,
                          const void* b1, const void* w2, const void* b2,
                          const int* __restrict__ flags, float* __restrict__ out) {
  int i = blockIdx.x * blockDim.x + threadIdx.x;
  if (i >= 65920) return;
  const void* src; int off; int fl;
  if (i < 32768)      { src = wn; off = 0;     fl = flags[1]; }
  else if (i < 32896) { src = bn; off = 32768; fl = flags[2]; }
  else if (i < 49280) { src = w1; off = 32896; fl = flags[3]; }
  else if (i < 49408) { src = b1; off = 49280; fl = flags[4]; }
  else if (i < 65792) { src = w2; off = 49408; fl = flags[5]; }
  else                { src = b2; off = 65792; fl = flags[6]; }
  int j = i - off;
  out[i] = fl ? bf2f(((const ushort_t*)src)[j]) : ((const float*)src)[j];
}

// ---------------- CSR build ----------------

__global__ void k_deg(const int* __restrict__ dst, int* __restrict__ deg) {
  int e = blockIdx.x * blockDim.x + threadIdx.x;
  if (e < N_EDGES) atomicAdd(&deg[dst[e]], 1);
}

__global__ void k_partial(const int* __restrict__ deg, int* __restrict__ partial) {
  __shared__ int lds[256];
  int b = blockIdx.x, t = threadIdx.x;
  int base = b * SCAN_CHUNK + t * 4;
  int s = 0;
#pragma unroll
  for (int i = 0; i < 4; i++) {
    int idx = base + i;
    if (idx < N_NODES) s += deg[idx];
  }
  lds[t] = s;
  __syncthreads();
  for (int off = 128; off > 0; off >>= 1) {
    if (t < off) lds[t] += lds[t + off];
    __syncthreads();
  }
  if (t == 0) partial[b] = lds[0];
}

__global__ void k_scan_part(int* __restrict__ partial, int* __restrict__ row_start) {
  if (threadIdx.x == 0) {
    int run = 0;
    for (int i = 0; i < N_CHUNKS; i++) {
      int v = partial[i];
      partial[i] = run;
      run += v;
    }
    row_start[N_NODES] = run;  // == N_EDGES
  }
}

__global__ void k_scan_final(const int* __restrict__ deg, const int* __restrict__ partial,
                             int* __restrict__ row_start, float* __restrict__ dinv) {
  __shared__ int lds[256];
  int b = blockIdx.x, t = threadIdx.x;
  int base = b * SCAN_CHUNK + t * 4;
  int v[4];
  int s = 0;
#pragma unroll
  for (int i = 0; i < 4; i++) {
    int idx = base + i;
    v[i] = (idx < N_NODES) ? deg[idx] : 0;
    s += v[i];
  }
  lds[t] = s;
  __syncthreads();
  for (int off = 1; off < 256; off <<= 1) {
    int add = (t >= off) ? lds[t - off] : 0;
    __syncthreads();
    lds[t] += add;
    __syncthreads();
  }
  int excl = lds[t] - s + partial[b];
#pragma unroll
  for (int i = 0; i < 4; i++) {
    int idx = base + i;
    if (idx < N_NODES) {
      row_start[idx] = excl;
      dinv[idx] = rsqrtf((float)(v[i] + 1));  // +1 self-loop
      excl += v[i];
    }
  }
}

__global__ void k_fill(const int* __restrict__ src, const int* __restrict__ dst,
                       const int* __restrict__ row_start, int* __restrict__ cursor,
                       int* __restrict__ csr) {
  int e = blockIdx.x * blockDim.x + threadIdx.x;
  if (e < N_EDGES) {
    int d = dst[e];
    int pos = atomicAdd(&cursor[d], 1);
    csr[row_start[d] + pos] = src[e];
  }
}

// ---------------- register-tiled GEMM: out[n][j] = sum_k X[n][k] W[j][k] (+bias)
// Tile: 128 j x 32 nodes per block (256 threads). Each thread: acc[4][4]
//   j = (tid&31) + 32*r, n = (tid>>5) + 8*s.
// LDS rows stride 36 floats (16B-aligned float4 rows).
// x compute-reads broadcast (2 addrs/wave); w compute-reads are b128.
template <int KDIM, bool GATHER, bool HAS_BIAS>
__global__ __launch_bounds__(256) void k_gemm_tiled(
    const float* __restrict__ Xf, const void* __restrict__ Xv,
    const int* __restrict__ tokens, const int* __restrict__ flags,
    const float* __restrict__ W, const float* __restrict__ bias,
    float* __restrict__ out) {
  __shared__ float w_lds[128 * 36];  // 18,432 B
  __shared__ float x_lds[32 * 36];   //  4,608 B
  int tid = threadIdx.x;
  int tj = tid & 31;
  int tn = tid >> 5;
  int node0 = blockIdx.x * 32;

  // staging roles: 8 threads per row (16B each)
  int sn = tid >> 3;     // 0..31
  int kk0s = (tid & 7) * 4;

  bool valid_sn = (node0 + sn) < N_NODES;
  int tok = 0, fl = 0;
  if (GATHER) {
    tok = valid_sn ? tokens[node0 + sn] : 0;
    fl = flags[0];
  }

  float acc[4][4];
#pragma unroll
  for (int r = 0; r < 4; r++)
#pragma unroll
    for (int s = 0; s < 4; s++) acc[r][s] = 0.f;

  for (int k0 = 0; k0 < KDIM; k0 += 32) {
    __syncthreads();
    // stage W: 128 rows x 32 cols
#pragma unroll
    for (int rr = 0; rr < 4; rr++) {
      int j = (tid >> 3) + 32 * rr;
      float4 wv = *(const float4*)&W[j * KDIM + k0 + kk0s];
      *(float4*)&w_lds[j * 36 + kk0s] = wv;
    }
    // stage X: 32 rows x 32 cols
    float4 xv = make_float4(0.f, 0.f, 0.f, 0.f);
    if (GATHER) {
      if (fl) {
        const ushort_t* eb = (const ushort_t*)Xv;
        const ushort_t* p = &eb[(size_t)tok * KDIM + k0 + kk0s];
        xv = make_float4(bf2f(p[0]), bf2f(p[1]), bf2f(p[2]), bf2f(p[3]));
      } else {
        const float* ef = (const float*)Xv;
        xv = *(const float4*)&ef[(size_t)tok * KDIM + k0 + kk0s];
      }
      if (!valid_sn) xv = make_float4(0.f, 0.f, 0.f, 0.f);
    } else if (valid_sn) {
      xv = *(const float4*)&Xf[(size_t)(node0 + sn) * KDIM + k0 + kk0s];
    }
    *(float4*)&x_lds[sn * 36 + kk0s] = xv;
    __syncthreads();
    // compute
#pragma unroll
    for (int kk = 0; kk < 32; kk += 4) {
      float4 wr[4], xr[4];
#pragma unroll
      for (int r = 0; r < 4; r++)
        wr[r] = *(const float4*)&w_lds[(tj + 32 * r) * 36 + kk];
#pragma unroll
      for (int s = 0; s < 4; s++)
        xr[s] = *(const float4*)&x_lds[(tn + 8 * s) * 36 + kk];
#pragma unroll
      for (int r = 0; r < 4; r++)
#pragma unroll
        for (int s = 0; s < 4; s++)
          acc[r][s] += wr[r].x * xr[s].x + wr[r].y * xr[s].y +
                       wr[r].z * xr[s].z + wr[r].w * xr[s].w;
    }
  }
  // epilogue
#pragma unroll
  for (int s = 0; s < 4; s++) {
    int node = node0 + tn + 8 * s;
    if (node < N_NODES) {
#pragma unroll
      for (int r = 0; r < 4; r++) {
        int j = tj + 32 * r;
        float v = acc[r][s];
        if (HAS_BIAS) v += bias[j];
        out[(size_t)node * D + j] = v;
      }
    }
  }
}

// ---------------- aggregation ----------------
// out[d] = sum_{s->d} dinv[s]dinv[d] t[s] + dinv[d]^2 t[d] + b  (one wave per d)
// CSR indices + dinv prefetched lane-parallel, broadcast via shfl.
template <bool RELU>
__global__ __launch_bounds__(256) void k_aggregate(
    const float* __restrict__ t, const int* __restrict__ row_start,
    const int* __restrict__ csr, const float* __restrict__ dinv,
    const float* __restrict__ bias, float* __restrict__ out) {
  int wave = threadIdx.x >> 6;
  int lane = threadIdx.x & 63;
  int node = blockIdx.x * 4 + wave;
  if (node >= N_NODES) return;
  float di = dinv[node];
  const float2* t2 = (const float2*)t;
  float2 acc;
  {
    float2 v = t2[(size_t)node * 64 + lane];  // self-loop
    float w = di * di;
    acc.x = w * v.x;
    acc.y = w * v.y;
  }
  int e0 = row_start[node], e1 = row_start[node + 1];
  for (int base = e0; base < e1; base += 64) {
    int cnt = min(64, e1 - base);
    int sidx = 0;
    float dv = 0.f;
    if (lane < cnt) {
      sidx = csr[base + lane];
      dv = dinv[sidx];
    }
    for (int i = 0; i < cnt; i++) {
      int s = __shfl(sidx, i);
      float w = di * __shfl(dv, i);
      float2 v = t2[(size_t)s * 64 + lane];
      acc.x += w * v.x;
      acc.y += w * v.y;
    }
  }
  acc.x += bias[2 * lane];
  acc.y += bias[2 * lane + 1];
  if (RELU) {
    acc.x = fmaxf(acc.x, 0.f);
    acc.y = fmaxf(acc.y, 0.f);
  }
  *(float2*)&out[(size_t)node * D + 2 * lane] = acc;
}

extern "C" void kernel_launch(void* const* d_in, const int* in_sizes, int n_in,
                              void* d_out, int out_size, void* d_ws, size_t ws_size,
                              hipStream_t stream) {
  const int* tokens = (const int*)d_in[0];
  const int* edge = (const int*)d_in[1];  // [2][E]
  const void* embed = d_in[2];
  const void* Wn = d_in[3];
  const void* bn = d_in[4];
  const void* w1 = d_in[5];
  const void* b1 = d_in[6];
  const void* w2 = d_in[7];
  const void* b2 = d_in[8];
  float* out = (float*)d_out;  // float32 output per reference dtype

  const int* src = edge;
  const int* dst = edge + N_EDGES;

  char* ws = (char*)d_ws;
  float* A = (float*)ws;                       // 25,600,000 B
  float* B = (float*)(ws + 25600000);          // 25,600,000 B
  float* dinv = (float*)(ws + 51200000);       // 200,000 B
  int* row_start = (int*)(ws + 51400064);      // 200,004 B
  int* degcur = (int*)(ws + 51600192);         // 200,000 B (deg, then cursor)
  int* csr = (int*)(ws + 51800256);            // 2,400,000 B
  int* partial = (int*)(ws + 54200320);        // 196 B
  int* flags = (int*)(ws + 54200576);          // 28 B
  float* wf = (float*)(ws + 54200640);         // 65,920 floats
  const float* Wnf = wf;
  const float* bnf = wf + 32768;
  const float* w1f = wf + 32896;
  const float* b1f = wf + 49280;
  const float* w2f = wf + 49408;
  const float* b2f = wf + 65792;

  const int GGRID = (N_NODES + 31) / 32;  // 1563

  // --- dtype detect + canonicalize params to fp32 ---
  k_detect<<<1, 256, 0, stream>>>(embed, Wn, bn, w1, b1, w2, b2, flags);
  k_convert<<<(65920 + 255) / 256, 256, 0, stream>>>(Wn, bn, w1, b1, w2, b2, flags, wf);

  // --- CSR build (shared by both convs) ---
  hipMemsetAsync(degcur, 0, N_NODES * sizeof(int), stream);
  k_deg<<<(N_EDGES + 255) / 256, 256, 0, stream>>>(dst, degcur);
  k_partial<<<N_CHUNKS, 256, 0, stream>>>(degcur, partial);
  k_scan_part<<<1, 64, 0, stream>>>(partial, row_start);
  k_scan_final<<<N_CHUNKS, 256, 0, stream>>>(degcur, partial, row_start, dinv);
  hipMemsetAsync(degcur, 0, N_NODES * sizeof(int), stream);
  k_fill<<<(N_EDGES + 255) / 256, 256, 0, stream>>>(src, dst, row_start, degcur, csr);

  // --- x0 = embed[tokens] @ Wn^T + bn -> A ---
  k_gemm_tiled<D_IN, true, true><<<GGRID, 256, 0, stream>>>(
      nullptr, embed, tokens, flags, Wnf, bnf, A);

  // --- conv1: t = x0 @ w1^T -> B ; aggregate + b1 + relu -> A ---
  k_gemm_tiled<D, false, false><<<GGRID, 256, 0, stream>>>(
      A, nullptr, nullptr, nullptr, w1f, nullptr, B);
  k_aggregate<true><<<(N_NODES + 3) / 4, 256, 0, stream>>>(
      B, row_start, csr, dinv, b1f, A);

  // --- conv2: t = x1 @ w2^T -> B ; aggregate + b2 -> out (fp32) ---
  k_gemm_tiled<D, false, false><<<GGRID, 256, 0, stream>>>(
      A, nullptr, nullptr, nullptr, w2f, nullptr, B);
  k_aggregate<false><<<(N_NODES + 3) / 4, 256, 0, stream>>>(
      B, row_start, csr, dinv, b2f, out);
}

// Round 5
// 363.783 us; speedup vs baseline: 1.6342x; 1.2677x over previous
//
#include <hip/hip_runtime.h>
#include <hip/hip_bf16.h>

#define N_NODES 50000
#define N_EDGES 600000
#define D_IN 256
#define D 128

#define SCAN_CHUNK 1024
#define N_CHUNKS ((N_NODES + SCAN_CHUNK - 1) / SCAN_CHUNK)  // 49

typedef unsigned short ushort_t;
typedef __attribute__((ext_vector_type(8))) short bf16x8;
typedef __attribute__((ext_vector_type(16))) float f32x16;

__device__ __forceinline__ float bf2f(ushort_t u) {
  union { unsigned int i; float f; } v;
  v.i = ((unsigned int)u) << 16;
  return v.f;
}
__device__ __forceinline__ ushort_t f2bf(float f) {
  union { float f; unsigned int i; } v;
  v.f = f;
  unsigned int x = v.i;
  unsigned int r = (x + 0x7FFFu + ((x >> 16) & 1u)) >> 16;  // RNE
  return (ushort_t)r;
}

// ---------------- dtype detection ----------------
__global__ void k_detect(const void* e, const void* wn, const void* bn,
                         const void* w1, const void* b1, const void* w2,
                         const void* b2, int* flags) {
  const void* ptrs[7] = {e, wn, bn, w1, b1, w2, b2};
  const int ns[7] = {12800000, 32768, 128, 16384, 128, 16384, 128};
  __shared__ int red[256];
  int t = threadIdx.x;
  for (int a = 0; a < 7; a++) {
    int pn = ns[a] < 2048 ? ns[a] : 2048;
    const ushort_t* p = (const ushort_t*)ptrs[a];
    int cnt = 0;
    for (int i = t; i < pn; i += 256) {
      ushort_t u = p[i];
      int ex = (u >> 7) & 0xFF;
      if ((u & 0x7FFF) == 0 || (ex >= 100 && ex <= 130)) cnt++;
    }
    red[t] = cnt;
    __syncthreads();
    for (int off = 128; off > 0; off >>= 1) {
      if (t < off) red[t] += red[t + off];
      __syncthreads();
    }
    if (t == 0) flags[a] = (red[0] * 100 >= pn * 85) ? 1 : 0;
    __syncthreads();
  }
}

// Canonicalize weights/biases to fp32 + emit bf16 hi/lo split for W matrices.
// Float offsets in `out`: Wn [0,32768) bn [32768,32896) w1 [32896,49280)
//                         b1 [49280,49408) w2 [49408,65792) b2 [65792,65920)
__global__ void k_convert(const void* wn, const void* bn, const void* w1,
                          const void* b1, const void* w2, const void* b2,
                          const int* __restrict__ flags, float* __restrict__ out,
                          ushort_t* __restrict__ WnH, ushort_t* __restrict__ WnL,
                          ushort_t* __restrict__ w1H, ushort_t* __restrict__ w1L,
                          ushort_t* __restrict__ w2H, ushort_t* __restrict__ w2L) {
  int i = blockIdx.x * blockDim.x + threadIdx.x;
  if (i >= 65920) return;
  const void* src; int off; int fl; int which;
  if (i < 32768)      { src = wn; off = 0;     fl = flags[1]; which = 0; }
  else if (i < 32896) { src = bn; off = 32768; fl = flags[2]; which = -1; }
  else if (i < 49280) { src = w1; off = 32896; fl = flags[3]; which = 1; }
  else if (i < 49408) { src = b1; off = 49280; fl = flags[4]; which = -1; }
  else if (i < 65792) { src = w2; off = 49408; fl = flags[5]; which = 2; }
  else                { src = b2; off = 65792; fl = flags[6]; which = -1; }
  int j = i - off;
  float v = fl ? bf2f(((const ushort_t*)src)[j]) : ((const float*)src)[j];
  out[i] = v;
  if (which >= 0) {
    ushort_t h = f2bf(v);
    ushort_t l = f2bf(v - bf2f(h));
    if (which == 0)      { WnH[j] = h; WnL[j] = l; }
    else if (which == 1) { w1H[j] = h; w1L[j] = l; }
    else                 { w2H[j] = h; w2L[j] = l; }
  }
}

// ---------------- CSR build ----------------

__global__ void k_deg(const int* __restrict__ dst, int* __restrict__ deg) {
  int e = blockIdx.x * blockDim.x + threadIdx.x;
  if (e < N_EDGES) atomicAdd(&deg[dst[e]], 1);
}

__global__ void k_partial(const int* __restrict__ deg, int* __restrict__ partial) {
  __shared__ int lds[256];
  int b = blockIdx.x, t = threadIdx.x;
  int base = b * SCAN_CHUNK + t * 4;
  int s = 0;
#pragma unroll
  for (int i = 0; i < 4; i++) {
    int idx = base + i;
    if (idx < N_NODES) s += deg[idx];
  }
  lds[t] = s;
  __syncthreads();
  for (int off = 128; off > 0; off >>= 1) {
    if (t < off) lds[t] += lds[t + off];
    __syncthreads();
  }
  if (t == 0) partial[b] = lds[0];
}

__global__ void k_scan_part(int* __restrict__ partial, int* __restrict__ row_start) {
  if (threadIdx.x == 0) {
    int run = 0;
    for (int i = 0; i < N_CHUNKS; i++) {
      int v = partial[i];
      partial[i] = run;
      run += v;
    }
    row_start[N_NODES] = run;  // == N_EDGES
  }
}

__global__ void k_scan_final(const int* __restrict__ deg, const int* __restrict__ partial,
                             int* __restrict__ row_start, float* __restrict__ dinv) {
  __shared__ int lds[256];
  int b = blockIdx.x, t = threadIdx.x;
  int base = b * SCAN_CHUNK + t * 4;
  int v[4];
  int s = 0;
#pragma unroll
  for (int i = 0; i < 4; i++) {
    int idx = base + i;
    v[i] = (idx < N_NODES) ? deg[idx] : 0;
    s += v[i];
  }
  lds[t] = s;
  __syncthreads();
  for (int off = 1; off < 256; off <<= 1) {
    int add = (t >= off) ? lds[t - off] : 0;
    __syncthreads();
    lds[t] += add;
    __syncthreads();
  }
  int excl = lds[t] - s + partial[b];
#pragma unroll
  for (int i = 0; i < 4; i++) {
    int idx = base + i;
    if (idx < N_NODES) {
      row_start[idx] = excl;
      dinv[idx] = rsqrtf((float)(v[i] + 1));  // +1 self-loop
      excl += v[i];
    }
  }
}

__global__ void k_fill(const int* __restrict__ src, const int* __restrict__ dst,
                       const int* __restrict__ row_start, int* __restrict__ cursor,
                       int* __restrict__ csr) {
  int e = blockIdx.x * blockDim.x + threadIdx.x;
  if (e < N_EDGES) {
    int d = dst[e];
    int pos = atomicAdd(&cursor[d], 1);
    csr[row_start[d] + pos] = src[e];
  }
}

// ---------------- MFMA split-bf16 GEMM: out[n][j] = sum_k X[n][k] W[j][k] (+bias)
// X = Xh+Xl, W = Wh+Wl (bf16 splits); acc = Xh*Wh + Xh*Wl + Xl*Wh (fp32 MFMA acc).
// Block: 32 nodes x 128 j, 4 waves; wave w owns j in [32w, 32w+32).
// mfma_f32_32x32x16_bf16: A/B frag [m=lane&31][k=(lane>>5)*8+i];
// C/D: col=lane&31, row=(reg&3)+8*(reg>>2)+4*(lane>>5).
template <int KDIM, bool GATHER, bool HAS_BIAS>
__global__ __launch_bounds__(256) void k_gemm_mfma(
    const float* __restrict__ Xf, const void* __restrict__ Xv,
    const int* __restrict__ tokens, const int* __restrict__ flags,
    const ushort_t* __restrict__ Wh, const ushort_t* __restrict__ Wl,
    const float* __restrict__ bias, float* __restrict__ out) {
  __shared__ __align__(16) ushort_t wh_lds[128 * 40];  // 10,240 B
  __shared__ __align__(16) ushort_t wl_lds[128 * 40];
  __shared__ __align__(16) ushort_t xh_lds[32 * 40];   //  2,560 B
  __shared__ __align__(16) ushort_t xl_lds[32 * 40];
  __shared__ int tok_lds[32];

  int tid = threadIdx.x;
  int lane = tid & 63;
  int wv = tid >> 6;  // wave 0..3
  int node0 = blockIdx.x * 32;

  int fl = 0;
  if (GATHER) {
    if (tid < 32) tok_lds[tid] = tokens[min(node0 + tid, N_NODES - 1)];
    fl = flags[0];  // wave-uniform
  }

  f32x16 acc;
#pragma unroll
  for (int r = 0; r < 16; r++) acc[r] = 0.f;

  // staging roles
  int wrow = tid >> 1;            // 0..127 (W row = j)
  int wc0 = (tid & 1) * 16;       // bf16 col offset within 32-tile
  int xrow = tid >> 3;            // 0..31 (X row = node)
  int xc0 = (tid & 7) * 4;        // fp32/bf16 col offset

  // fragment roles
  int fm = lane & 31;
  int fq = lane >> 5;  // 0/1

  for (int k0 = 0; k0 < KDIM; k0 += 32) {
    __syncthreads();
    // --- stage W split tile: 128 rows x 32 cols ---
    {
      const ushort_t* gh = &Wh[wrow * KDIM + k0 + wc0];
      const ushort_t* gl = &Wl[wrow * KDIM + k0 + wc0];
      uint4 h0 = *(const uint4*)gh;
      uint4 h1 = *(const uint4*)(gh + 8);
      uint4 l0 = *(const uint4*)gl;
      uint4 l1 = *(const uint4*)(gl + 8);
      *(uint4*)&wh_lds[wrow * 40 + wc0] = h0;
      *(uint4*)&wh_lds[wrow * 40 + wc0 + 8] = h1;
      *(uint4*)&wl_lds[wrow * 40 + wc0] = l0;
      *(uint4*)&wl_lds[wrow * 40 + wc0 + 8] = l1;
    }
    // --- stage X split tile: 32 rows x 32 cols ---
    if (GATHER && fl) {
      // embed already bf16: hi = value, lo = 0 (exact split)
      const ushort_t* eb = (const ushort_t*)Xv;
      int tk = tok_lds[xrow];
      ushort4 hv = *(const ushort4*)&eb[(size_t)tk * KDIM + k0 + xc0];
      ushort4 zv; zv.x = 0; zv.y = 0; zv.z = 0; zv.w = 0;
      *(ushort4*)&xh_lds[xrow * 40 + xc0] = hv;
      *(ushort4*)&xl_lds[xrow * 40 + xc0] = zv;
    } else {
      float4 v;
      if (GATHER) {
        const float* ef = (const float*)Xv;
        int tk = tok_lds[xrow];
        v = *(const float4*)&ef[(size_t)tk * KDIM + k0 + xc0];
      } else {
        int n = min(node0 + xrow, N_NODES - 1);
        v = *(const float4*)&Xf[(size_t)n * KDIM + k0 + xc0];
      }
      ushort4 h, l;
      h.x = f2bf(v.x); l.x = f2bf(v.x - bf2f(h.x));
      h.y = f2bf(v.y); l.y = f2bf(v.y - bf2f(h.y));
      h.z = f2bf(v.z); l.z = f2bf(v.z - bf2f(h.z));
      h.w = f2bf(v.w); l.w = f2bf(v.w - bf2f(h.w));
      *(ushort4*)&xh_lds[xrow * 40 + xc0] = h;
      *(ushort4*)&xl_lds[xrow * 40 + xc0] = l;
    }
    __syncthreads();
    // --- compute: 2 K-steps of 16 ---
#pragma unroll
    for (int s = 0; s < 2; s++) {
      int ko = s * 16 + fq * 8;  // element offset in LDS row
      bf16x8 ah = *(const bf16x8*)&xh_lds[fm * 40 + ko];
      bf16x8 al = *(const bf16x8*)&xl_lds[fm * 40 + ko];
      bf16x8 bh = *(const bf16x8*)&wh_lds[(wv * 32 + fm) * 40 + ko];
      bf16x8 bl = *(const bf16x8*)&wl_lds[(wv * 32 + fm) * 40 + ko];
      acc = __builtin_amdgcn_mfma_f32_32x32x16_bf16(ah, bh, acc, 0, 0, 0);
      acc = __builtin_amdgcn_mfma_f32_32x32x16_bf16(ah, bl, acc, 0, 0, 0);
      acc = __builtin_amdgcn_mfma_f32_32x32x16_bf16(al, bh, acc, 0, 0, 0);
    }
  }
  // --- epilogue ---
  int col = lane & 31;
  int j = wv * 32 + col;
  float bv = HAS_BIAS ? bias[j] : 0.f;
  int rbase = fq * 4;
#pragma unroll
  for (int r = 0; r < 16; r++) {
    int row = (r & 3) + 8 * (r >> 2) + rbase;
    int node = node0 + row;
    if (node < N_NODES) out[(size_t)node * D + j] = acc[r] + bv;
  }
}

// ---------------- aggregation ----------------
// out[d] = sum_{s->d} dinv[s]dinv[d] t[s] + dinv[d]^2 t[d] + b  (one wave per d)
template <bool RELU>
__global__ __launch_bounds__(256) void k_aggregate(
    const float* __restrict__ t, const int* __restrict__ row_start,
    const int* __restrict__ csr, const float* __restrict__ dinv,
    const float* __restrict__ bias, float* __restrict__ out) {
  int wave = threadIdx.x >> 6;
  int lane = threadIdx.x & 63;
  int node = blockIdx.x * 4 + wave;
  if (node >= N_NODES) return;
  float di = dinv[node];
  const float2* t2 = (const float2*)t;
  float2 acc;
  {
    float2 v = t2[(size_t)node * 64 + lane];  // self-loop
    float w = di * di;
    acc.x = w * v.x;
    acc.y = w * v.y;
  }
  int e0 = row_start[node], e1 = row_start[node + 1];
  for (int base = e0; base < e1; base += 64) {
    int cnt = min(64, e1 - base);
    int sidx = 0;
    float dv = 0.f;
    if (lane < cnt) {
      sidx = csr[base + lane];
      dv = dinv[sidx];
    }
    for (int i = 0; i < cnt; i++) {
      int s = __shfl(sidx, i);
      float w = di * __shfl(dv, i);
      float2 v = t2[(size_t)s * 64 + lane];
      acc.x += w * v.x;
      acc.y += w * v.y;
    }
  }
  acc.x += bias[2 * lane];
  acc.y += bias[2 * lane + 1];
  if (RELU) {
    acc.x = fmaxf(acc.x, 0.f);
    acc.y = fmaxf(acc.y, 0.f);
  }
  *(float2*)&out[(size_t)node * D + 2 * lane] = acc;
}

extern "C" void kernel_launch(void* const* d_in, const int* in_sizes, int n_in,
                              void* d_out, int out_size, void* d_ws, size_t ws_size,
                              hipStream_t stream) {
  const int* tokens = (const int*)d_in[0];
  const int* edge = (const int*)d_in[1];  // [2][E]
  const void* embed = d_in[2];
  const void* Wn = d_in[3];
  const void* bn = d_in[4];
  const void* w1 = d_in[5];
  const void* b1 = d_in[6];
  const void* w2 = d_in[7];
  const void* b2 = d_in[8];
  float* out = (float*)d_out;  // float32 output

  const int* src = edge;
  const int* dst = edge + N_EDGES;

  char* ws = (char*)d_ws;
  float* A = (float*)ws;                       // 25,600,000 B
  float* B = (float*)(ws + 25600000);          // 25,600,000 B
  float* dinv = (float*)(ws + 51200000);       // 200,000 B
  int* row_start = (int*)(ws + 51400064);      // 200,004 B
  int* degcur = (int*)(ws + 51600192);         // 200,000 B
  int* csr = (int*)(ws + 51800256);            // 2,400,000 B
  int* partial = (int*)(ws + 54200320);        // 196 B
  int* flags = (int*)(ws + 54200576);          // 28 B
  float* wf = (float*)(ws + 54200640);         // 65,920 floats = 263,680 B
  ushort_t* WnH = (ushort_t*)(ws + 54464320);  // 65,536 B
  ushort_t* WnL = (ushort_t*)(ws + 54529856);  // 65,536 B
  ushort_t* w1H = (ushort_t*)(ws + 54595392);  // 32,768 B
  ushort_t* w1L = (ushort_t*)(ws + 54628160);  // 32,768 B
  ushort_t* w2H = (ushort_t*)(ws + 54660928);  // 32,768 B
  ushort_t* w2L = (ushort_t*)(ws + 54693696);  // 32,768 B -> end 54,726,464
  const float* bnf = wf + 32768;
  const float* b1f = wf + 49280;
  const float* b2f = wf + 65792;

  const int GGRID = (N_NODES + 31) / 32;  // 1563

  // --- dtype detect + canonicalize + W split ---
  k_detect<<<1, 256, 0, stream>>>(embed, Wn, bn, w1, b1, w2, b2, flags);
  k_convert<<<(65920 + 255) / 256, 256, 0, stream>>>(
      Wn, bn, w1, b1, w2, b2, flags, wf, WnH, WnL, w1H, w1L, w2H, w2L);

  // --- CSR build (shared by both convs) ---
  hipMemsetAsync(degcur, 0, N_NODES * sizeof(int), stream);
  k_deg<<<(N_EDGES + 255) / 256, 256, 0, stream>>>(dst, degcur);
  k_partial<<<N_CHUNKS, 256, 0, stream>>>(degcur, partial);
  k_scan_part<<<1, 64, 0, stream>>>(partial, row_start);
  k_scan_final<<<N_CHUNKS, 256, 0, stream>>>(degcur, partial, row_start, dinv);
  hipMemsetAsync(degcur, 0, N_NODES * sizeof(int), stream);
  k_fill<<<(N_EDGES + 255) / 256, 256, 0, stream>>>(src, dst, row_start, degcur, csr);

  // --- x0 = embed[tokens] @ Wn^T + bn -> A ---
  k_gemm_mfma<D_IN, true, true><<<GGRID, 256, 0, stream>>>(
      nullptr, embed, tokens, flags, WnH, WnL, bnf, A);

  // --- conv1: t = x0 @ w1^T -> B ; aggregate + b1 + relu -> A ---
  k_gemm_mfma<D, false, false><<<GGRID, 256, 0, stream>>>(
      A, nullptr, nullptr, nullptr, w1H, w1L, nullptr, B);
  k_aggregate<true><<<(N_NODES + 3) / 4, 256, 0, stream>>>(
      B, row_start, csr, dinv, b1f, A);

  // --- conv2: t = x1 @ w2^T -> B ; aggregate + b2 -> out (fp32) ---
  k_gemm_mfma<D, false, false><<<GGRID, 256, 0, stream>>>(
      A, nullptr, nullptr, nullptr, w2H, w2L, nullptr, B);
  k_aggregate<false><<<(N_NODES + 3) / 4, 256, 0, stream>>>(
      B, row_start, csr, dinv, b2f, out);
}

// Round 6
// 347.927 us; speedup vs baseline: 1.7087x; 1.0456x over previous
//
#include <hip/hip_runtime.h>
#include <hip/hip_bf16.h>

#define N_NODES 50000
#define N_EDGES 600000
#define D_IN 256
#define D 128

#define SCAN_CHUNK 1024
#define N_CHUNKS ((N_NODES + SCAN_CHUNK - 1) / SCAN_CHUNK)  // 49

typedef unsigned short ushort_t;
typedef __attribute__((ext_vector_type(8))) short bf16x8;
typedef __attribute__((ext_vector_type(16))) float f32x16;

__device__ __forceinline__ float bf2f(ushort_t u) {
  union { unsigned int i; float f; } v;
  v.i = ((unsigned int)u) << 16;
  return v.f;
}
__device__ __forceinline__ ushort_t f2bf(float f) {
  union { float f; unsigned int i; } v;
  v.f = f;
  unsigned int x = v.i;
  unsigned int r = (x + 0x7FFFu + ((x >> 16) & 1u)) >> 16;  // RNE
  return (ushort_t)r;
}

// ---------------- dtype detection (insurance; expected all-fp32) ----------------
__global__ void k_detect(const void* e, const void* wn, const void* bn,
                         const void* w1, const void* b1, const void* w2,
                         const void* b2, int* flags) {
  const void* ptrs[7] = {e, wn, bn, w1, b1, w2, b2};
  const int ns[7] = {12800000, 32768, 128, 16384, 128, 16384, 128};
  __shared__ int red[256];
  int t = threadIdx.x;
  for (int a = 0; a < 7; a++) {
    int pn = ns[a] < 2048 ? ns[a] : 2048;
    const ushort_t* p = (const ushort_t*)ptrs[a];
    int cnt = 0;
    for (int i = t; i < pn; i += 256) {
      ushort_t u = p[i];
      int ex = (u >> 7) & 0xFF;
      if ((u & 0x7FFF) == 0 || (ex >= 100 && ex <= 130)) cnt++;
    }
    red[t] = cnt;
    __syncthreads();
    for (int off = 128; off > 0; off >>= 1) {
      if (t < off) red[t] += red[t + off];
      __syncthreads();
    }
    if (t == 0) flags[a] = (red[0] * 100 >= pn * 85) ? 1 : 0;
    __syncthreads();
  }
}

// Split weights into bf16 hi/lo; canonicalize biases to fp32 ws.
// i: [0,32768) Wn  [32768,49152) w1  [49152,65536) w2
//    [65536,65664) bn  [65664,65792) b1  [65792,65920) b2
__global__ void k_split(const void* wn, const void* w1, const void* w2,
                        const void* bn, const void* b1, const void* b2,
                        const int* __restrict__ flags,
                        ushort_t* __restrict__ WnH, ushort_t* __restrict__ WnL,
                        ushort_t* __restrict__ w1H, ushort_t* __restrict__ w1L,
                        ushort_t* __restrict__ w2H, ushort_t* __restrict__ w2L,
                        float* __restrict__ bias_ws) {
  int i = blockIdx.x * blockDim.x + threadIdx.x;
  if (i >= 65920) return;
  if (i < 65536) {
    const void* src; int j; int fl; ushort_t *H, *L;
    if (i < 32768)      { src = wn; j = i;         fl = flags[1]; H = WnH; L = WnL; }
    else if (i < 49152) { src = w1; j = i - 32768; fl = flags[3]; H = w1H; L = w1L; }
    else                { src = w2; j = i - 49152; fl = flags[5]; H = w2H; L = w2L; }
    float v = fl ? bf2f(((const ushort_t*)src)[j]) : ((const float*)src)[j];
    ushort_t h = f2bf(v);
    H[j] = h;
    L[j] = f2bf(v - bf2f(h));
  } else {
    const void* src; int j; int fl;
    if (i < 65664)      { src = bn; j = i - 65536; fl = flags[2]; }
    else if (i < 65792) { src = b1; j = i - 65664; fl = flags[4]; }
    else                { src = b2; j = i - 65792; fl = flags[6]; }
    bias_ws[i - 65536] = fl ? bf2f(((const ushort_t*)src)[j]) : ((const float*)src)[j];
  }
}

// ---------------- CSR build ----------------

__global__ void k_deg(const int* __restrict__ dst, int* __restrict__ deg) {
  int e = blockIdx.x * blockDim.x + threadIdx.x;
  if (e < N_EDGES) atomicAdd(&deg[dst[e]], 1);
}

__global__ void k_partial(const int* __restrict__ deg, int* __restrict__ partial) {
  __shared__ int lds[256];
  int b = blockIdx.x, t = threadIdx.x;
  int base = b * SCAN_CHUNK + t * 4;
  int s = 0;
#pragma unroll
  for (int i = 0; i < 4; i++) {
    int idx = base + i;
    if (idx < N_NODES) s += deg[idx];
  }
  lds[t] = s;
  __syncthreads();
  for (int off = 128; off > 0; off >>= 1) {
    if (t < off) lds[t] += lds[t + off];
    __syncthreads();
  }
  if (t == 0) partial[b] = lds[0];
}

__global__ void k_scan_part(int* __restrict__ partial, int* __restrict__ row_start) {
  if (threadIdx.x == 0) {
    int run = 0;
    for (int i = 0; i < N_CHUNKS; i++) {
      int v = partial[i];
      partial[i] = run;
      run += v;
    }
    row_start[N_NODES] = run;
  }
}

__global__ void k_scan_final(const int* __restrict__ deg, const int* __restrict__ partial,
                             int* __restrict__ row_start, float* __restrict__ dinv) {
  __shared__ int lds[256];
  int b = blockIdx.x, t = threadIdx.x;
  int base = b * SCAN_CHUNK + t * 4;
  int v[4];
  int s = 0;
#pragma unroll
  for (int i = 0; i < 4; i++) {
    int idx = base + i;
    v[i] = (idx < N_NODES) ? deg[idx] : 0;
    s += v[i];
  }
  lds[t] = s;
  __syncthreads();
  for (int off = 1; off < 256; off <<= 1) {
    int add = (t >= off) ? lds[t - off] : 0;
    __syncthreads();
    lds[t] += add;
    __syncthreads();
  }
  int excl = lds[t] - s + partial[b];
#pragma unroll
  for (int i = 0; i < 4; i++) {
    int idx = base + i;
    if (idx < N_NODES) {
      row_start[idx] = excl;
      dinv[idx] = rsqrtf((float)(v[i] + 1));  // +1 self-loop
      excl += v[i];
    }
  }
}

__global__ void k_fill(const int* __restrict__ src, const int* __restrict__ dst,
                       const int* __restrict__ row_start, int* __restrict__ cursor,
                       int* __restrict__ csr) {
  int e = blockIdx.x * blockDim.x + threadIdx.x;
  if (e < N_EDGES) {
    int d = dst[e];
    int pos = atomicAdd(&cursor[d], 1);
    csr[row_start[d] + pos] = src[e];
  }
}

// ---------------- MFMA split-bf16 GEMM ----------------
// out[n][j] = sum_k X[n][k] W[j][k] (+bias).  acc = Xh*Wh + Xh*Wl + Xl*Wh.
// Block: 32 nodes x 128 j, 4 waves; wave wv owns j in [32wv, 32wv+32).
// EMBED=true : X gathered from fp32 (or bf16) embed via tokens; output = hi/lo
//              bf16 split arrays (+bias). KDIM=256.
// EMBED=false: X pre-split hi/lo bf16 arrays; output = bf16 matrix. KDIM=128.
template <int KDIM, bool EMBED>
__global__ __launch_bounds__(256) void k_gemm_mfma(
    const ushort_t* __restrict__ Xh, const ushort_t* __restrict__ Xl,
    const void* __restrict__ Xv, const int* __restrict__ tokens,
    const int* __restrict__ flags,
    const ushort_t* __restrict__ Wh, const ushort_t* __restrict__ Wl,
    const float* __restrict__ bias,
    ushort_t* __restrict__ OutH, ushort_t* __restrict__ OutL,
    ushort_t* __restrict__ OutT) {
  __shared__ __align__(16) ushort_t wh_lds[128 * 40];
  __shared__ __align__(16) ushort_t wl_lds[128 * 40];
  __shared__ __align__(16) ushort_t xh_lds[32 * 40];
  __shared__ __align__(16) ushort_t xl_lds[32 * 40];
  __shared__ int tok_lds[32];

  int tid = threadIdx.x;
  int lane = tid & 63;
  int wv = tid >> 6;
  int node0 = blockIdx.x * 32;

  int fl = 0;
  if (EMBED) {
    if (tid < 32) tok_lds[tid] = tokens[min(node0 + tid, N_NODES - 1)];
    fl = flags[0];
  }

  f32x16 acc;
#pragma unroll
  for (int r = 0; r < 16; r++) acc[r] = 0.f;

  int wrow = tid >> 1;
  int wc0 = (tid & 1) * 16;
  int xrow = tid >> 3;
  int xc0 = (tid & 7) * 4;

  int fm = lane & 31;
  int fq = lane >> 5;

  for (int k0 = 0; k0 < KDIM; k0 += 32) {
    __syncthreads();
    // stage W split tile: 128 rows x 32 cols
    {
      const ushort_t* gh = &Wh[wrow * KDIM + k0 + wc0];
      const ushort_t* gl = &Wl[wrow * KDIM + k0 + wc0];
      uint4 h0 = *(const uint4*)gh;
      uint4 h1 = *(const uint4*)(gh + 8);
      uint4 l0 = *(const uint4*)gl;
      uint4 l1 = *(const uint4*)(gl + 8);
      *(uint4*)&wh_lds[wrow * 40 + wc0] = h0;
      *(uint4*)&wh_lds[wrow * 40 + wc0 + 8] = h1;
      *(uint4*)&wl_lds[wrow * 40 + wc0] = l0;
      *(uint4*)&wl_lds[wrow * 40 + wc0 + 8] = l1;
    }
    // stage X split tile: 32 rows x 32 cols
    if (EMBED) {
      int tk = tok_lds[xrow];
      if (fl) {
        const ushort_t* eb = (const ushort_t*)Xv;
        ushort4 hv = *(const ushort4*)&eb[(size_t)tk * KDIM + k0 + xc0];
        ushort4 zv; zv.x = 0; zv.y = 0; zv.z = 0; zv.w = 0;
        *(ushort4*)&xh_lds[xrow * 40 + xc0] = hv;
        *(ushort4*)&xl_lds[xrow * 40 + xc0] = zv;
      } else {
        const float* ef = (const float*)Xv;
        float4 v = *(const float4*)&ef[(size_t)tk * KDIM + k0 + xc0];
        ushort4 h, l;
        h.x = f2bf(v.x); l.x = f2bf(v.x - bf2f(h.x));
        h.y = f2bf(v.y); l.y = f2bf(v.y - bf2f(h.y));
        h.z = f2bf(v.z); l.z = f2bf(v.z - bf2f(h.z));
        h.w = f2bf(v.w); l.w = f2bf(v.w - bf2f(h.w));
        *(ushort4*)&xh_lds[xrow * 40 + xc0] = h;
        *(ushort4*)&xl_lds[xrow * 40 + xc0] = l;
      }
    } else {
      int n = min(node0 + xrow, N_NODES - 1);
      ushort4 h = *(const ushort4*)&Xh[(size_t)n * D + k0 + xc0];
      ushort4 l = *(const ushort4*)&Xl[(size_t)n * D + k0 + xc0];
      *(ushort4*)&xh_lds[xrow * 40 + xc0] = h;
      *(ushort4*)&xl_lds[xrow * 40 + xc0] = l;
    }
    __syncthreads();
#pragma unroll
    for (int s = 0; s < 2; s++) {
      int ko = s * 16 + fq * 8;
      bf16x8 ah = *(const bf16x8*)&xh_lds[fm * 40 + ko];
      bf16x8 al = *(const bf16x8*)&xl_lds[fm * 40 + ko];
      bf16x8 bh = *(const bf16x8*)&wh_lds[(wv * 32 + fm) * 40 + ko];
      bf16x8 bl = *(const bf16x8*)&wl_lds[(wv * 32 + fm) * 40 + ko];
      acc = __builtin_amdgcn_mfma_f32_32x32x16_bf16(ah, bh, acc, 0, 0, 0);
      acc = __builtin_amdgcn_mfma_f32_32x32x16_bf16(ah, bl, acc, 0, 0, 0);
      acc = __builtin_amdgcn_mfma_f32_32x32x16_bf16(al, bh, acc, 0, 0, 0);
    }
  }
  // epilogue: C/D col=lane&31, row=(r&3)+8*(r>>2)+4*fq
  int col = lane & 31;
  int j = wv * 32 + col;
  float bv = EMBED ? bias[j] : 0.f;
  int rbase = fq * 4;
#pragma unroll
  for (int r = 0; r < 16; r++) {
    int row = (r & 3) + 8 * (r >> 2) + rbase;
    int node = node0 + row;
    if (node < N_NODES) {
      float v = acc[r] + bv;
      if (EMBED) {
        ushort_t h = f2bf(v);
        OutH[(size_t)node * D + j] = h;
        OutL[(size_t)node * D + j] = f2bf(v - bf2f(h));
      } else {
        OutT[(size_t)node * D + j] = f2bf(v);
      }
    }
  }
}

// ---------------- aggregation ----------------
// out[d] = sum_{s->d} dinv[s]dinv[d] t[s] + dinv[d]^2 t[d] + b  (one wave per d)
// t is bf16 [N,128]; lane handles cols {2*lane, 2*lane+1} via packed uint.
// SPLIT_OUT: write hi/lo bf16 arrays (x1 for GEMM2). Else fp32 out.
template <bool RELU, bool SPLIT_OUT>
__global__ __launch_bounds__(256) void k_aggregate(
    const ushort_t* __restrict__ t, const int* __restrict__ row_start,
    const int* __restrict__ csr, const float* __restrict__ dinv,
    const float* __restrict__ bias, float* __restrict__ out_f,
    ushort_t* __restrict__ outH, ushort_t* __restrict__ outL) {
  int wave = threadIdx.x >> 6;
  int lane = threadIdx.x & 63;
  int node = blockIdx.x * 4 + wave;
  if (node >= N_NODES) return;
  float di = dinv[node];
  const unsigned int* tu = (const unsigned int*)t;
  float ax, ay;
  {
    unsigned int u = tu[(size_t)node * 64 + lane];  // self-loop
    float w = di * di;
    ax = w * bf2f((ushort_t)(u & 0xFFFF));
    ay = w * bf2f((ushort_t)(u >> 16));
  }
  int e0 = row_start[node], e1 = row_start[node + 1];
  for (int base = e0; base < e1; base += 64) {
    int cnt = min(64, e1 - base);
    int sidx = 0;
    float dv = 0.f;
    if (lane < cnt) {
      sidx = csr[base + lane];
      dv = dinv[sidx];
    }
    for (int i = 0; i < cnt; i++) {
      int s = __shfl(sidx, i);
      float w = di * __shfl(dv, i);
      unsigned int u = tu[(size_t)s * 64 + lane];
      ax += w * bf2f((ushort_t)(u & 0xFFFF));
      ay += w * bf2f((ushort_t)(u >> 16));
    }
  }
  ax += bias[2 * lane];
  ay += bias[2 * lane + 1];
  if (RELU) {
    ax = fmaxf(ax, 0.f);
    ay = fmaxf(ay, 0.f);
  }
  if (SPLIT_OUT) {
    ushort2 h, l;
    h.x = f2bf(ax); l.x = f2bf(ax - bf2f(h.x));
    h.y = f2bf(ay); l.y = f2bf(ay - bf2f(h.y));
    *(ushort2*)&outH[(size_t)node * D + 2 * lane] = h;
    *(ushort2*)&outL[(size_t)node * D + 2 * lane] = l;
  } else {
    float2 o; o.x = ax; o.y = ay;
    *(float2*)&out_f[(size_t)node * D + 2 * lane] = o;
  }
}

extern "C" void kernel_launch(void* const* d_in, const int* in_sizes, int n_in,
                              void* d_out, int out_size, void* d_ws, size_t ws_size,
                              hipStream_t stream) {
  const int* tokens = (const int*)d_in[0];
  const int* edge = (const int*)d_in[1];  // [2][E]
  const void* embed = d_in[2];
  const void* Wn = d_in[3];
  const void* bn = d_in[4];
  const void* w1 = d_in[5];
  const void* b1 = d_in[6];
  const void* w2 = d_in[7];
  const void* b2 = d_in[8];
  float* out = (float*)d_out;  // fp32 output

  const int* src = edge;
  const int* dst = edge + N_EDGES;

  char* ws = (char*)d_ws;
  ushort_t* Xh = (ushort_t*)ws;                    // 12,800,000 B
  ushort_t* Xl = (ushort_t*)(ws + 12800000);       // 12,800,000 B
  ushort_t* T  = (ushort_t*)(ws + 25600000);       // 12,800,000 B
  float* dinv = (float*)(ws + 38400000);           // 200,000 B
  int* row_start = (int*)(ws + 38600064);          // 200,004 B (pad)
  int* degcur = (int*)(ws + 38800128);             // 400,000 B (deg | cursor)
  int* csr = (int*)(ws + 39200128);                // 2,400,000 B
  int* partial = (int*)(ws + 41600192);            // 196 B
  int* flags = (int*)(ws + 41600448);              // 28 B
  ushort_t* WnH = (ushort_t*)(ws + 41600512);      // 65,536 B
  ushort_t* WnL = (ushort_t*)(ws + 41666048);      // 65,536 B
  ushort_t* w1H = (ushort_t*)(ws + 41731584);      // 32,768 B
  ushort_t* w1L = (ushort_t*)(ws + 41764352);      // 32,768 B
  ushort_t* w2H = (ushort_t*)(ws + 41797120);      // 32,768 B
  ushort_t* w2L = (ushort_t*)(ws + 41829888);      // 32,768 B
  float* bias_ws = (float*)(ws + 41862656);        // 1,536 B
  const float* bnf = bias_ws;
  const float* b1f = bias_ws + 128;
  const float* b2f = bias_ws + 256;
  int* deg = degcur;
  int* cursor = degcur + N_NODES;

  const int GGRID = (N_NODES + 31) / 32;  // 1563

  // --- dtype detect + weight split + bias canonicalize ---
  k_detect<<<1, 256, 0, stream>>>(embed, Wn, bn, w1, b1, w2, b2, flags);
  k_split<<<(65920 + 255) / 256, 256, 0, stream>>>(
      Wn, w1, w2, bn, b1, b2, flags, WnH, WnL, w1H, w1L, w2H, w2L, bias_ws);

  // --- CSR build (one memset covers deg + cursor) ---
  hipMemsetAsync(degcur, 0, 2 * N_NODES * sizeof(int), stream);
  k_deg<<<(N_EDGES + 255) / 256, 256, 0, stream>>>(dst, deg);
  k_partial<<<N_CHUNKS, 256, 0, stream>>>(deg, partial);
  k_scan_part<<<1, 64, 0, stream>>>(partial, row_start);
  k_scan_final<<<N_CHUNKS, 256, 0, stream>>>(deg, partial, row_start, dinv);
  k_fill<<<(N_EDGES + 255) / 256, 256, 0, stream>>>(src, dst, row_start, cursor, csr);

  // --- x0 = embed[tokens] @ Wn^T + bn -> (Xh, Xl) ---
  k_gemm_mfma<D_IN, true><<<GGRID, 256, 0, stream>>>(
      nullptr, nullptr, embed, tokens, flags, WnH, WnL, bnf, Xh, Xl, nullptr);

  // --- conv1: t1 = x0 @ w1^T -> T (bf16) ; aggregate+b1+relu -> (Xh, Xl) ---
  k_gemm_mfma<D, false><<<GGRID, 256, 0, stream>>>(
      Xh, Xl, nullptr, nullptr, nullptr, w1H, w1L, nullptr, nullptr, nullptr, T);
  k_aggregate<true, true><<<(N_NODES + 3) / 4, 256, 0, stream>>>(
      T, row_start, csr, dinv, b1f, nullptr, Xh, Xl);

  // --- conv2: t2 = x1 @ w2^T -> T (bf16) ; aggregate+b2 -> out (fp32) ---
  k_gemm_mfma<D, false><<<GGRID, 256, 0, stream>>>(
      Xh, Xl, nullptr, nullptr, nullptr, w2H, w2L, nullptr, nullptr, nullptr, T);
  k_aggregate<false, false><<<(N_NODES + 3) / 4, 256, 0, stream>>>(
      T, row_start, csr, dinv, b2f, out, nullptr, nullptr);
}

// Round 7
// 320.674 us; speedup vs baseline: 1.8539x; 1.0850x over previous
//
#include <hip/hip_runtime.h>
#include <hip/hip_bf16.h>

#define N_NODES 50000
#define N_EDGES 600000
#define D_IN 256
#define D 128

#define SCAN_CHUNK 1024
#define N_CHUNKS ((N_NODES + SCAN_CHUNK - 1) / SCAN_CHUNK)  // 49

typedef unsigned short ushort_t;
typedef __attribute__((ext_vector_type(8))) short bf16x8;
typedef __attribute__((ext_vector_type(16))) float f32x16;

__device__ __forceinline__ float bf2f(ushort_t u) {
  union { unsigned int i; float f; } v;
  v.i = ((unsigned int)u) << 16;
  return v.f;
}
__device__ __forceinline__ ushort_t f2bf(float f) {
  union { float f; unsigned int i; } v;
  v.f = f;
  unsigned int x = v.i;
  unsigned int r = (x + 0x7FFFu + ((x >> 16) & 1u)) >> 16;  // RNE
  return (ushort_t)r;
}

// ---------------- dtype detection (insurance; expected all-fp32) ----------------
__global__ void k_detect(const void* e, const void* wn, const void* bn,
                         const void* w1, const void* b1, const void* w2,
                         const void* b2, int* flags) {
  const void* ptrs[7] = {e, wn, bn, w1, b1, w2, b2};
  const int ns[7] = {12800000, 32768, 128, 16384, 128, 16384, 128};
  __shared__ int red[256];
  int t = threadIdx.x;
  for (int a = 0; a < 7; a++) {
    int pn = ns[a] < 2048 ? ns[a] : 2048;
    const ushort_t* p = (const ushort_t*)ptrs[a];
    int cnt = 0;
    for (int i = t; i < pn; i += 256) {
      ushort_t u = p[i];
      int ex = (u >> 7) & 0xFF;
      if ((u & 0x7FFF) == 0 || (ex >= 100 && ex <= 130)) cnt++;
    }
    red[t] = cnt;
    __syncthreads();
    for (int off = 128; off > 0; off >>= 1) {
      if (t < off) red[t] += red[t + off];
      __syncthreads();
    }
    if (t == 0) flags[a] = (red[0] * 100 >= pn * 85) ? 1 : 0;
    __syncthreads();
  }
}

// Split weights into bf16 hi/lo; canonicalize biases to fp32 ws.
__global__ void k_split(const void* wn, const void* w1, const void* w2,
                        const void* bn, const void* b1, const void* b2,
                        const int* __restrict__ flags,
                        ushort_t* __restrict__ WnH, ushort_t* __restrict__ WnL,
                        ushort_t* __restrict__ w1H, ushort_t* __restrict__ w1L,
                        ushort_t* __restrict__ w2H, ushort_t* __restrict__ w2L,
                        float* __restrict__ bias_ws) {
  int i = blockIdx.x * blockDim.x + threadIdx.x;
  if (i >= 65920) return;
  if (i < 65536) {
    const void* src; int j; int fl; ushort_t *H, *L;
    if (i < 32768)      { src = wn; j = i;         fl = flags[1]; H = WnH; L = WnL; }
    else if (i < 49152) { src = w1; j = i - 32768; fl = flags[3]; H = w1H; L = w1L; }
    else                { src = w2; j = i - 49152; fl = flags[5]; H = w2H; L = w2L; }
    float v = fl ? bf2f(((const ushort_t*)src)[j]) : ((const float*)src)[j];
    ushort_t h = f2bf(v);
    H[j] = h;
    L[j] = f2bf(v - bf2f(h));
  } else {
    const void* src; int j; int fl;
    if (i < 65664)      { src = bn; j = i - 65536; fl = flags[2]; }
    else if (i < 65792) { src = b1; j = i - 65664; fl = flags[4]; }
    else                { src = b2; j = i - 65792; fl = flags[6]; }
    bias_ws[i - 65536] = fl ? bf2f(((const ushort_t*)src)[j]) : ((const float*)src)[j];
  }
}

// ---------------- CSR build ----------------

__global__ void k_deg(const int* __restrict__ dst, int* __restrict__ deg) {
  int e = blockIdx.x * blockDim.x + threadIdx.x;
  if (e < N_EDGES) atomicAdd(&deg[dst[e]], 1);
}

__global__ void k_partial(const int* __restrict__ deg, int* __restrict__ partial) {
  __shared__ int lds[256];
  int b = blockIdx.x, t = threadIdx.x;
  int base = b * SCAN_CHUNK + t * 4;
  int s = 0;
#pragma unroll
  for (int i = 0; i < 4; i++) {
    int idx = base + i;
    if (idx < N_NODES) s += deg[idx];
  }
  lds[t] = s;
  __syncthreads();
  for (int off = 128; off > 0; off >>= 1) {
    if (t < off) lds[t] += lds[t + off];
    __syncthreads();
  }
  if (t == 0) partial[b] = lds[0];
}

__global__ void k_scan_part(int* __restrict__ partial, int* __restrict__ row_start) {
  if (threadIdx.x == 0) {
    int run = 0;
    for (int i = 0; i < N_CHUNKS; i++) {
      int v = partial[i];
      partial[i] = run;
      run += v;
    }
    row_start[N_NODES] = run;
  }
}

__global__ void k_scan_final(const int* __restrict__ deg, const int* __restrict__ partial,
                             int* __restrict__ row_start, float* __restrict__ dinv) {
  __shared__ int lds[256];
  int b = blockIdx.x, t = threadIdx.x;
  int base = b * SCAN_CHUNK + t * 4;
  int v[4];
  int s = 0;
#pragma unroll
  for (int i = 0; i < 4; i++) {
    int idx = base + i;
    v[i] = (idx < N_NODES) ? deg[idx] : 0;
    s += v[i];
  }
  lds[t] = s;
  __syncthreads();
  for (int off = 1; off < 256; off <<= 1) {
    int add = (t >= off) ? lds[t - off] : 0;
    __syncthreads();
    lds[t] += add;
    __syncthreads();
  }
  int excl = lds[t] - s + partial[b];
#pragma unroll
  for (int i = 0; i < 4; i++) {
    int idx = base + i;
    if (idx < N_NODES) {
      row_start[idx] = excl;
      dinv[idx] = rsqrtf((float)(v[i] + 1));  // +1 self-loop
      excl += v[i];
    }
  }
}

__global__ void k_fill(const int* __restrict__ src, const int* __restrict__ dst,
                       const int* __restrict__ row_start, int* __restrict__ cursor,
                       int* __restrict__ csr) {
  int e = blockIdx.x * blockDim.x + threadIdx.x;
  if (e < N_EDGES) {
    int d = dst[e];
    int pos = atomicAdd(&cursor[d], 1);
    csr[row_start[d] + pos] = src[e];
  }
}

// ---------------- MFMA split-bf16 GEMM ----------------
// out[n][j] = sum_k X[n][k] W[j][k] (+bias).  acc = Xh*Wh + Xh*Wl + Xl*Wh.
// Block: 32 nodes x 128 j, 4 waves; wave wv owns j in [32wv, 32wv+32).
// EMBED=true : X gathered from embed via tokens; out = hi/lo split (+bias).
// EMBED=false: X pre-split hi/lo; out = bf16 T, PRE-SCALED by dinv[node].
template <int KDIM, bool EMBED>
__global__ __launch_bounds__(256) void k_gemm_mfma(
    const ushort_t* __restrict__ Xh, const ushort_t* __restrict__ Xl,
    const void* __restrict__ Xv, const int* __restrict__ tokens,
    const int* __restrict__ flags,
    const ushort_t* __restrict__ Wh, const ushort_t* __restrict__ Wl,
    const float* __restrict__ bias, const float* __restrict__ dinvp,
    ushort_t* __restrict__ OutH, ushort_t* __restrict__ OutL,
    ushort_t* __restrict__ OutT) {
  __shared__ __align__(16) ushort_t wh_lds[128 * 40];
  __shared__ __align__(16) ushort_t wl_lds[128 * 40];
  __shared__ __align__(16) ushort_t xh_lds[32 * 40];
  __shared__ __align__(16) ushort_t xl_lds[32 * 40];
  __shared__ int tok_lds[32];

  int tid = threadIdx.x;
  int lane = tid & 63;
  int wv = tid >> 6;
  int node0 = blockIdx.x * 32;

  int fl = 0;
  if (EMBED) {
    if (tid < 32) tok_lds[tid] = tokens[min(node0 + tid, N_NODES - 1)];
    fl = flags[0];
  }

  f32x16 acc;
#pragma unroll
  for (int r = 0; r < 16; r++) acc[r] = 0.f;

  int wrow = tid >> 1;
  int wc0 = (tid & 1) * 16;
  int xrow = tid >> 3;
  int xc0 = (tid & 7) * 4;

  int fm = lane & 31;
  int fq = lane >> 5;

  for (int k0 = 0; k0 < KDIM; k0 += 32) {
    __syncthreads();
    // stage W split tile: 128 rows x 32 cols
    {
      const ushort_t* gh = &Wh[wrow * KDIM + k0 + wc0];
      const ushort_t* gl = &Wl[wrow * KDIM + k0 + wc0];
      uint4 h0 = *(const uint4*)gh;
      uint4 h1 = *(const uint4*)(gh + 8);
      uint4 l0 = *(const uint4*)gl;
      uint4 l1 = *(const uint4*)(gl + 8);
      *(uint4*)&wh_lds[wrow * 40 + wc0] = h0;
      *(uint4*)&wh_lds[wrow * 40 + wc0 + 8] = h1;
      *(uint4*)&wl_lds[wrow * 40 + wc0] = l0;
      *(uint4*)&wl_lds[wrow * 40 + wc0 + 8] = l1;
    }
    // stage X split tile: 32 rows x 32 cols
    if (EMBED) {
      int tk = tok_lds[xrow];
      if (fl) {
        const ushort_t* eb = (const ushort_t*)Xv;
        ushort4 hv = *(const ushort4*)&eb[(size_t)tk * KDIM + k0 + xc0];
        ushort4 zv; zv.x = 0; zv.y = 0; zv.z = 0; zv.w = 0;
        *(ushort4*)&xh_lds[xrow * 40 + xc0] = hv;
        *(ushort4*)&xl_lds[xrow * 40 + xc0] = zv;
      } else {
        const float* ef = (const float*)Xv;
        float4 v = *(const float4*)&ef[(size_t)tk * KDIM + k0 + xc0];
        ushort4 h, l;
        h.x = f2bf(v.x); l.x = f2bf(v.x - bf2f(h.x));
        h.y = f2bf(v.y); l.y = f2bf(v.y - bf2f(h.y));
        h.z = f2bf(v.z); l.z = f2bf(v.z - bf2f(h.z));
        h.w = f2bf(v.w); l.w = f2bf(v.w - bf2f(h.w));
        *(ushort4*)&xh_lds[xrow * 40 + xc0] = h;
        *(ushort4*)&xl_lds[xrow * 40 + xc0] = l;
      }
    } else {
      int n = min(node0 + xrow, N_NODES - 1);
      ushort4 h = *(const ushort4*)&Xh[(size_t)n * D + k0 + xc0];
      ushort4 l = *(const ushort4*)&Xl[(size_t)n * D + k0 + xc0];
      *(ushort4*)&xh_lds[xrow * 40 + xc0] = h;
      *(ushort4*)&xl_lds[xrow * 40 + xc0] = l;
    }
    __syncthreads();
#pragma unroll
    for (int s = 0; s < 2; s++) {
      int ko = s * 16 + fq * 8;
      bf16x8 ah = *(const bf16x8*)&xh_lds[fm * 40 + ko];
      bf16x8 al = *(const bf16x8*)&xl_lds[fm * 40 + ko];
      bf16x8 bh = *(const bf16x8*)&wh_lds[(wv * 32 + fm) * 40 + ko];
      bf16x8 bl = *(const bf16x8*)&wl_lds[(wv * 32 + fm) * 40 + ko];
      acc = __builtin_amdgcn_mfma_f32_32x32x16_bf16(ah, bh, acc, 0, 0, 0);
      acc = __builtin_amdgcn_mfma_f32_32x32x16_bf16(ah, bl, acc, 0, 0, 0);
      acc = __builtin_amdgcn_mfma_f32_32x32x16_bf16(al, bh, acc, 0, 0, 0);
    }
  }
  // epilogue: C/D col=lane&31, row=(r&3)+8*(r>>2)+4*fq
  int col = lane & 31;
  int j = wv * 32 + col;
  float bv = EMBED ? bias[j] : 0.f;
  int rbase = fq * 4;
#pragma unroll
  for (int r = 0; r < 16; r++) {
    int row = (r & 3) + 8 * (r >> 2) + rbase;
    int node = node0 + row;
    if (node < N_NODES) {
      if (EMBED) {
        float v = acc[r] + bv;
        ushort_t h = f2bf(v);
        OutH[(size_t)node * D + j] = h;
        OutL[(size_t)node * D + j] = f2bf(v - bf2f(h));
      } else {
        // pre-scale by dinv[node] so aggregation needs no per-source weight
        OutT[(size_t)node * D + j] = f2bf(acc[r] * dinvp[node]);
      }
    }
  }
}

// ---------------- aggregation ----------------
// T is pre-scaled by dinv: out[d] = dinv[d]*(T[d] + sum_{s->d} T[s]) + b.
// One wave per node; lane handles packed cols {2l,2l+1}; edge loop unrolled x4
// to keep ~4 gathers in flight (latency-bound at ~500cyc avg L2/HBM mix).
template <bool RELU, bool SPLIT_OUT>
__global__ __launch_bounds__(256) void k_aggregate(
    const ushort_t* __restrict__ t, const int* __restrict__ row_start,
    const int* __restrict__ csr, const float* __restrict__ dinv,
    const float* __restrict__ bias, float* __restrict__ out_f,
    ushort_t* __restrict__ outH, ushort_t* __restrict__ outL) {
  int wave = threadIdx.x >> 6;
  int lane = threadIdx.x & 63;
  int node = blockIdx.x * 4 + wave;
  if (node >= N_NODES) return;
  const unsigned int* tu = (const unsigned int*)t;
  float ax, ay;
  {
    unsigned int u = tu[(size_t)node * 64 + lane];  // self-loop (pre-scaled)
    ax = bf2f((ushort_t)(u & 0xFFFF));
    ay = bf2f((ushort_t)(u >> 16));
  }
  int e0 = row_start[node], e1 = row_start[node + 1];
  for (int base = e0; base < e1; base += 64) {
    int cnt = min(64, e1 - base);
    int sidx = (lane < cnt) ? csr[base + lane] : 0;
    int i = 0;
    for (; i + 4 <= cnt; i += 4) {
      int s0 = __shfl(sidx, i);
      int s1 = __shfl(sidx, i + 1);
      int s2 = __shfl(sidx, i + 2);
      int s3 = __shfl(sidx, i + 3);
      unsigned int u0 = tu[(size_t)s0 * 64 + lane];
      unsigned int u1 = tu[(size_t)s1 * 64 + lane];
      unsigned int u2 = tu[(size_t)s2 * 64 + lane];
      unsigned int u3 = tu[(size_t)s3 * 64 + lane];
      ax += bf2f((ushort_t)(u0 & 0xFFFF));
      ay += bf2f((ushort_t)(u0 >> 16));
      ax += bf2f((ushort_t)(u1 & 0xFFFF));
      ay += bf2f((ushort_t)(u1 >> 16));
      ax += bf2f((ushort_t)(u2 & 0xFFFF));
      ay += bf2f((ushort_t)(u2 >> 16));
      ax += bf2f((ushort_t)(u3 & 0xFFFF));
      ay += bf2f((ushort_t)(u3 >> 16));
    }
    for (; i < cnt; i++) {
      int s = __shfl(sidx, i);
      unsigned int u = tu[(size_t)s * 64 + lane];
      ax += bf2f((ushort_t)(u & 0xFFFF));
      ay += bf2f((ushort_t)(u >> 16));
    }
  }
  float di = dinv[node];
  ax = di * ax + bias[2 * lane];
  ay = di * ay + bias[2 * lane + 1];
  if (RELU) {
    ax = fmaxf(ax, 0.f);
    ay = fmaxf(ay, 0.f);
  }
  if (SPLIT_OUT) {
    ushort2 h, l;
    h.x = f2bf(ax); l.x = f2bf(ax - bf2f(h.x));
    h.y = f2bf(ay); l.y = f2bf(ay - bf2f(h.y));
    *(ushort2*)&outH[(size_t)node * D + 2 * lane] = h;
    *(ushort2*)&outL[(size_t)node * D + 2 * lane] = l;
  } else {
    float2 o; o.x = ax; o.y = ay;
    *(float2*)&out_f[(size_t)node * D + 2 * lane] = o;
  }
}

extern "C" void kernel_launch(void* const* d_in, const int* in_sizes, int n_in,
                              void* d_out, int out_size, void* d_ws, size_t ws_size,
                              hipStream_t stream) {
  const int* tokens = (const int*)d_in[0];
  const int* edge = (const int*)d_in[1];  // [2][E]
  const void* embed = d_in[2];
  const void* Wn = d_in[3];
  const void* bn = d_in[4];
  const void* w1 = d_in[5];
  const void* b1 = d_in[6];
  const void* w2 = d_in[7];
  const void* b2 = d_in[8];
  float* out = (float*)d_out;  // fp32 output

  const int* src = edge;
  const int* dst = edge + N_EDGES;

  char* ws = (char*)d_ws;
  ushort_t* Xh = (ushort_t*)ws;                    // 12,800,000 B
  ushort_t* Xl = (ushort_t*)(ws + 12800000);       // 12,800,000 B
  ushort_t* T  = (ushort_t*)(ws + 25600000);       // 12,800,000 B
  float* dinv = (float*)(ws + 38400000);           // 200,000 B
  int* row_start = (int*)(ws + 38600064);          // 200,004 B (pad)
  int* degcur = (int*)(ws + 38800128);             // 400,000 B (deg | cursor)
  int* csr = (int*)(ws + 39200128);                // 2,400,000 B
  int* partial = (int*)(ws + 41600192);            // 196 B
  int* flags = (int*)(ws + 41600448);              // 28 B
  ushort_t* WnH = (ushort_t*)(ws + 41600512);      // 65,536 B
  ushort_t* WnL = (ushort_t*)(ws + 41666048);      // 65,536 B
  ushort_t* w1H = (ushort_t*)(ws + 41731584);      // 32,768 B
  ushort_t* w1L = (ushort_t*)(ws + 41764352);      // 32,768 B
  ushort_t* w2H = (ushort_t*)(ws + 41797120);      // 32,768 B
  ushort_t* w2L = (ushort_t*)(ws + 41829888);      // 32,768 B
  float* bias_ws = (float*)(ws + 41862656);        // 1,536 B
  const float* bnf = bias_ws;
  const float* b1f = bias_ws + 128;
  const float* b2f = bias_ws + 256;
  int* deg = degcur;
  int* cursor = degcur + N_NODES;

  const int GGRID = (N_NODES + 31) / 32;  // 1563

  // --- dtype detect + weight split + bias canonicalize ---
  k_detect<<<1, 256, 0, stream>>>(embed, Wn, bn, w1, b1, w2, b2, flags);
  k_split<<<(65920 + 255) / 256, 256, 0, stream>>>(
      Wn, w1, w2, bn, b1, b2, flags, WnH, WnL, w1H, w1L, w2H, w2L, bias_ws);

  // --- CSR build (one memset covers deg + cursor) ---
  hipMemsetAsync(degcur, 0, 2 * N_NODES * sizeof(int), stream);
  k_deg<<<(N_EDGES + 255) / 256, 256, 0, stream>>>(dst, deg);
  k_partial<<<N_CHUNKS, 256, 0, stream>>>(deg, partial);
  k_scan_part<<<1, 64, 0, stream>>>(partial, row_start);
  k_scan_final<<<N_CHUNKS, 256, 0, stream>>>(deg, partial, row_start, dinv);
  k_fill<<<(N_EDGES + 255) / 256, 256, 0, stream>>>(src, dst, row_start, cursor, csr);

  // --- x0 = embed[tokens] @ Wn^T + bn -> (Xh, Xl) ---
  k_gemm_mfma<D_IN, true><<<GGRID, 256, 0, stream>>>(
      nullptr, nullptr, embed, tokens, flags, WnH, WnL, bnf, nullptr,
      Xh, Xl, nullptr);

  // --- conv1: T = (x0 @ w1^T)*dinv ; aggregate+b1+relu -> (Xh, Xl) ---
  k_gemm_mfma<D, false><<<GGRID, 256, 0, stream>>>(
      Xh, Xl, nullptr, nullptr, nullptr, w1H, w1L, nullptr, dinv,
      nullptr, nullptr, T);
  k_aggregate<true, true><<<(N_NODES + 3) / 4, 256, 0, stream>>>(
      T, row_start, csr, dinv, b1f, nullptr, Xh, Xl);

  // --- conv2: T = (x1 @ w2^T)*dinv ; aggregate+b2 -> out (fp32) ---
  k_gemm_mfma<D, false><<<GGRID, 256, 0, stream>>>(
      Xh, Xl, nullptr, nullptr, nullptr, w2H, w2L, nullptr, dinv,
      nullptr, nullptr, T);
  k_aggregate<false, false><<<(N_NODES + 3) / 4, 256, 0, stream>>>(
      T, row_start, csr, dinv, b2f, out, nullptr, nullptr);
}